// Round 17
// baseline (1291.442 us; speedup 1.0000x reference)
//
#include <hip/hip_runtime.h>
#include <hip/hip_cooperative_groups.h>
#include <hip/hip_fp16.h>

#define LEAKY 0.01f
#define BN_EPS 1e-5f
#define NB 512       // dst buckets
#define NW 512       // writer blocks (sort spans)
#define EMAX 4096    // max edges per bucket in LDS
#define BCAP 7168    // csr ints per bucket
#define GRID 1024    // cooperative grid attempt (4 blocks/CU x 256 CU)

typedef int v4i __attribute__((ext_vector_type(4)));
namespace cg = cooperative_groups;

struct Params {
  const int* src; const int* dst;
  unsigned* barr; int* bofs; int* csr; int2* seg2; float* dinv;
  double* st; __half* A; __half* B; __half* A2; float* out;
  const float* x; const float* W1; const float* b1;
  const float* gamma; const float* beta; const float* W2; const float* b2;
  int n, e, nper, gG, split;
};

// ================= shared device phase implementations =================

__device__ __forceinline__ void sort_phase(int wb, const int* __restrict__ src,
                                           const int* __restrict__ dst,
                                           unsigned* __restrict__ barr,
                                           int* __restrict__ bofs,
                                           double* __restrict__ st,
                                           __half* __restrict__ A,
                                           __half* __restrict__ A2,
                                           int e, int nper, int n, int* smem) {
  int t = threadIdx.x;
  int* lcnt = smem;
  int* lofs = smem + 512;
  int* lcur = smem + 1024;
  int* sd = smem + 1536;
  if (wb == 0 && t < 128) st[t] = 0.0;
  if (wb == 1 && t < 32) ((unsigned*)(A + (size_t)n * 64))[t] = 0u;
  if (wb == 2 && t < 32) ((unsigned*)(A2 + (size_t)n * 64))[t] = 0u;
  int S = (e + NW - 1) / NW;
  int s0 = wb * S, s1 = min(e, s0 + S);
  lcnt[t] = 0;
  lcnt[t + 256] = 0;
  lcur[t] = 0;
  lcur[t + 256] = 0;
  __syncthreads();
  for (int i = s0 + t; i < s1; i += 256) atomicAdd(&lcnt[dst[i] / nper], 1);
  __syncthreads();
  int c0 = lcnt[2 * t], c1 = lcnt[2 * t + 1];
  int ts = c0 + c1;
  sd[t] = ts;
  __syncthreads();
  for (int off = 1; off < 256; off <<= 1) {
    int x = (t >= off) ? sd[t - off] : 0;
    __syncthreads();
    sd[t] += x;
    __syncthreads();
  }
  int run = sd[t] - ts;
  lofs[2 * t] = run;
  lofs[2 * t + 1] = run + c0;
  bofs[wb * (NB + 1) + 2 * t] = run;
  bofs[wb * (NB + 1) + 2 * t + 1] = run + c0;
  if (t == 255) bofs[wb * (NB + 1) + NB] = sd[255];
  __syncthreads();
  for (int i = s0 + t; i < s1; i += 256) {
    int d = dst[i];
    int b = d / nper;
    int r = atomicAdd(&lcur[b], 1);
    barr[s0 + lofs[b] + r] = ((unsigned)src[i] << 9) | (unsigned)(d - b * nper);
  }
}

__device__ __forceinline__ void csrb_phase(int b, const unsigned* __restrict__ barr,
                                           const int* __restrict__ bofs,
                                           int* __restrict__ csr,
                                           int2* __restrict__ seg2,
                                           float* __restrict__ dinv,
                                           int n, int nper, int e, int* smem) {
  int t = threadIdx.x;
  int* eds = smem;             // [4096]
  int* cnt_ = smem + 4096;     // [256]
  int* base_ = smem + 4352;    // [256]
  int* sd = smem + 4608;       // [256]
  int* ssz = smem + 4864;      // [512]
  int* soff = smem + 5376;     // [512]
  int* sstart = smem + 5888;   // [512]
  int S = (e + NW - 1) / NW;
  int lo = b * nper;
  int nn = min(nper, n - lo);
  if (nn < 0) nn = 0;
  int sa0 = bofs[(2 * t) * (NB + 1) + b];
  int se0 = bofs[(2 * t) * (NB + 1) + b + 1];
  int sa1 = bofs[(2 * t + 1) * (NB + 1) + b];
  int se1 = bofs[(2 * t + 1) * (NB + 1) + b + 1];
  int v0 = se0 - sa0, v1 = se1 - sa1;
  sstart[2 * t] = sa0;
  sstart[2 * t + 1] = sa1;
  ssz[2 * t] = v0;
  ssz[2 * t + 1] = v1;
  int ts = v0 + v1;
  sd[t] = ts;
  __syncthreads();
  for (int off = 1; off < 256; off <<= 1) {
    int x = (t >= off) ? sd[t - off] : 0;
    __syncthreads();
    sd[t] += x;
    __syncthreads();
  }
  int run = sd[t] - ts;
  soff[2 * t] = run;
  soff[2 * t + 1] = run + v0;
  __syncthreads();
  int total = min(sd[255], EMAX);
  int g8 = t >> 3, l8 = t & 7;
  for (int wb = g8; wb < NW; wb += 32) {
    int sz = ssz[wb], of = soff[wb];
    const unsigned* rp = barr + (size_t)wb * S + sstart[wb];
    for (int k = l8; k < sz && of + k < EMAX; k += 8) eds[of + k] = (int)rp[k];
  }
  cnt_[t] = 0;
  __syncthreads();
  for (int i = t; i < total; i += 256) atomicAdd(&cnt_[eds[i] & 511], 1);
  __syncthreads();
  int c = cnt_[t];
  int pc = (t < nn) ? ((c + 15) & ~15) : 0;
  sd[t] = pc;
  __syncthreads();
  for (int off = 1; off < 256; off <<= 1) {
    int x = (t >= off) ? sd[t - off] : 0;
    __syncthreads();
    sd[t] += x;
    __syncthreads();
  }
  base_[t] = sd[t] - pc;
  __syncthreads();
  int bb = b * BCAP;
  if (t < nn) {
    int ba = bb + base_[t];
    seg2[lo + t] = make_int2(ba, ba + pc);
    dinv[lo + t] = rsqrtf((float)(c + 1));  // +1 self-loop
    for (int j = c; j < pc; j++) csr[ba + j] = n;  // sentinel -> zero row
  }
  __syncthreads();
  cnt_[t] = 0;
  __syncthreads();
  for (int i = t; i < total; i += 256) {
    int vv = eds[i];
    int lcl = vv & 511;
    int r = atomicAdd(&cnt_[lcl], 1);
    csr[bb + base_[lcl] + r] = vv >> 9;
  }
  if (b == 0 && t == 0) dinv[n] = 0.f;
}

__device__ __forceinline__ void gemm1_tile(int tile, const float* __restrict__ X,
                                           const float* __restrict__ W,
                                           __half* __restrict__ Y, int n, int* smem) {
  float(*Ws)[68] = (float(*)[68])smem;
  float(*Xs)[68] = (float(*)[68])(smem + 4352);
  int t = threadIdx.x;
  __syncthreads();
  int rowbase = tile * 64;
#pragma unroll
  for (int p = 0; p < 4; p++) {
    int idx = (p * 256 + t) * 4;
    *(float4*)&Ws[idx >> 6][idx & 63] = *(const float4*)&W[idx];
    int r = idx >> 6, c = idx & 63;
    int gr = rowbase + r;
    float4 v = (gr < n) ? *(const float4*)&X[(size_t)gr * 64 + c]
                        : make_float4(0.f, 0.f, 0.f, 0.f);
    *(float4*)&Xs[r][c] = v;
  }
  __syncthreads();
  int r = t >> 2, cq = t & 3;
  float acc[16];
#pragma unroll
  for (int j = 0; j < 16; j++) acc[j] = 0.f;
#pragma unroll 4
  for (int k = 0; k < 64; k++) {
    float xv = Xs[r][k];
#pragma unroll
    for (int j = 0; j < 16; j++) acc[j] += xv * Ws[k][cq * 16 + j];
  }
  int gr = rowbase + r;
  if (gr < n) {
    __half2 h2[8];
#pragma unroll
    for (int j = 0; j < 8; j++) h2[j] = __floats2half2_rn(acc[2 * j], acc[2 * j + 1]);
    __half* yp = &Y[(size_t)gr * 64 + cq * 16];
    *(int4*)yp = *(int4*)&h2[0];
    *(int4*)(yp + 8) = *(int4*)&h2[4];
  }
}

__device__ __forceinline__ void gemm2_tile(int tile, const __half* __restrict__ Xh,
                                           const float* __restrict__ W,
                                           __half* __restrict__ Y, int n,
                                           const float* __restrict__ dinv,
                                           const float* __restrict__ gamma,
                                           const float* __restrict__ beta,
                                           const float* smu, const float* sisd,
                                           int* smem) {
  float(*Ws)[68] = (float(*)[68])smem;
  float(*Xs)[68] = (float(*)[68])(smem + 4352);
  int t = threadIdx.x;
  __syncthreads();
  int rowbase = tile * 64;
#pragma unroll
  for (int p = 0; p < 4; p++) {
    int idx = (p * 256 + t) * 4;
    *(float4*)&Ws[idx >> 6][idx & 63] = *(const float4*)&W[idx];
  }
#pragma unroll
  for (int p = 0; p < 2; p++) {
    int idx = (p * 256 + t) * 8;
    int r = idx >> 6, c = idx & 63;
    int gr = rowbase + r;
    float vp[8];
    if (gr < n) {
      int4 hv = *(const int4*)&Xh[(size_t)gr * 64 + c];
      __half2* hp = (__half2*)&hv;
#pragma unroll
      for (int q = 0; q < 4; q++) {
        float2 f = __half22float2(hp[q]);
        vp[2 * q] = f.x;
        vp[2 * q + 1] = f.y;
      }
    } else {
#pragma unroll
      for (int q = 0; q < 8; q++) vp[q] = 0.f;
    }
#pragma unroll
    for (int q = 0; q < 8; q++) {
      float z = gamma[c + q] * (vp[q] - smu[c + q]) * sisd[c + q] + beta[c + q];
      Xs[r][c + q] = (z >= 0.f) ? z : LEAKY * z;
    }
  }
  __syncthreads();
  int r = t >> 2, cq = t & 3;
  float acc[16];
#pragma unroll
  for (int j = 0; j < 16; j++) acc[j] = 0.f;
#pragma unroll 4
  for (int k = 0; k < 64; k++) {
    float xv = Xs[r][k];
#pragma unroll
    for (int j = 0; j < 16; j++) acc[j] += xv * Ws[k][cq * 16 + j];
  }
  int gr = rowbase + r;
  if (gr < n) {
    float dv = dinv[gr];
    __half2 h2[8];
#pragma unroll
    for (int j = 0; j < 8; j++)
      h2[j] = __floats2half2_rn(acc[2 * j] * dv, acc[2 * j + 1] * dv);
    __half* yp = &Y[(size_t)gr * 64 + cq * 16];
    *(int4*)yp = *(int4*)&h2[0];
    *(int4*)(yp + 8) = *(int4*)&h2[4];
  }
}

template <bool WEIGHTED, bool FP16OUT>
__device__ __forceinline__ void agg_node(int i, const __half* __restrict__ H,
                                         void* __restrict__ Optr,
                                         const int2* __restrict__ seg2,
                                         const int* __restrict__ csr,
                                         const float* __restrict__ dinv,
                                         const float* __restrict__ bias, int n,
                                         int lane) {
  float di = dinv[i];
  int2 sg = seg2[i];
  int m = lane & 31;
  bool loA = lane < 32;
  float2 sf = __half22float2(*(const __half2*)&H[(size_t)i * 64 + 2 * m]);
  float sw = WEIGHTED ? di : 1.f;
  float a0 = loA ? sf.x * sw : 0.f;
  float a1 = loA ? sf.y * sw : 0.f;
  const v4i* cp = (const v4i*)csr;
  int j = sg.x >> 2, jend = sg.y >> 2;
  v4i q0 = cp[j];
  v4i q1 = cp[j + 1];
  v4i q2 = cp[j + 2];
  v4i q3 = cp[j + 3];
  for (; j < jend; j += 4) {
    v4i p0 = cp[j + 4];
    v4i p1 = cp[j + 5];
    v4i p2 = cp[j + 6];
    v4i p3 = cp[j + 7];
    int i0 = loA ? q0[0] : q0[1];
    int i1 = loA ? q0[2] : q0[3];
    int i2 = loA ? q1[0] : q1[1];
    int i3 = loA ? q1[2] : q1[3];
    int i4 = loA ? q2[0] : q2[1];
    int i5 = loA ? q2[2] : q2[3];
    int i6 = loA ? q3[0] : q3[1];
    int i7 = loA ? q3[2] : q3[3];
    float2 f0 = __half22float2(*(const __half2*)&H[(size_t)i0 * 64 + 2 * m]);
    float2 f1 = __half22float2(*(const __half2*)&H[(size_t)i1 * 64 + 2 * m]);
    float2 f2 = __half22float2(*(const __half2*)&H[(size_t)i2 * 64 + 2 * m]);
    float2 f3 = __half22float2(*(const __half2*)&H[(size_t)i3 * 64 + 2 * m]);
    float2 f4 = __half22float2(*(const __half2*)&H[(size_t)i4 * 64 + 2 * m]);
    float2 f5 = __half22float2(*(const __half2*)&H[(size_t)i5 * 64 + 2 * m]);
    float2 f6 = __half22float2(*(const __half2*)&H[(size_t)i6 * 64 + 2 * m]);
    float2 f7 = __half22float2(*(const __half2*)&H[(size_t)i7 * 64 + 2 * m]);
    if constexpr (WEIGHTED) {
      float w0 = dinv[i0], w1 = dinv[i1], w2 = dinv[i2], w3 = dinv[i3];
      float w4 = dinv[i4], w5 = dinv[i5], w6 = dinv[i6], w7 = dinv[i7];
      a0 += f0.x * w0 + f1.x * w1 + f2.x * w2 + f3.x * w3;
      a1 += f0.y * w0 + f1.y * w1 + f2.y * w2 + f3.y * w3;
      a0 += f4.x * w4 + f5.x * w5 + f6.x * w6 + f7.x * w7;
      a1 += f4.y * w4 + f5.y * w5 + f6.y * w6 + f7.y * w7;
    } else {
      a0 += f0.x + f1.x + f2.x + f3.x;
      a1 += f0.y + f1.y + f2.y + f3.y;
      a0 += f4.x + f5.x + f6.x + f7.x;
      a1 += f4.y + f5.y + f6.y + f7.y;
    }
    q0 = p0;
    q1 = p1;
    q2 = p2;
    q3 = p3;
  }
  a0 += __shfl_xor(a0, 32, 64);
  a1 += __shfl_xor(a1, 32, 64);
  if (loA) {
    float2 bv = *(const float2*)&bias[2 * m];
    float o0 = di * a0 + bv.x;
    float o1 = di * a1 + bv.y;
    if constexpr (FP16OUT) {
      ((__half2*)Optr)[(size_t)i * 32 + m] = __floats2half2_rn(o0, o1);
    } else {
      float2 o;
      o.x = o0;
      o.y = o1;
      *(float2*)&((float*)Optr)[(size_t)i * 64 + 2 * m] = o;
    }
  }
}

__device__ __forceinline__ void bnstats_phase(int bid, int nblk,
                                              const __half* __restrict__ B,
                                              double* __restrict__ st, int n,
                                              int* smem) {
  int t = threadIdx.x;
  double* ds0 = (double*)smem;
  double* ds1 = ds0 + 256;
  double* dq0 = ds0 + 512;
  double* dq1 = ds0 + 768;
  int m = t & 31, g = t >> 5;
  double s0 = 0.0, s1 = 0.0, q0 = 0.0, q1 = 0.0;
  const __half2* H2 = (const __half2*)B;
  for (int r = bid * 8 + g; r < n; r += nblk * 8) {
    float2 f = __half22float2(H2[(size_t)r * 32 + m]);
    s0 += f.x;
    s1 += f.y;
    q0 += (double)f.x * f.x;
    q1 += (double)f.y * f.y;
  }
  __syncthreads();
  ds0[g * 32 + m] = s0;
  ds1[g * 32 + m] = s1;
  dq0[g * 32 + m] = q0;
  dq1[g * 32 + m] = q1;
  __syncthreads();
  if (g == 0) {
    double a0 = 0, a1 = 0, b0 = 0, b1 = 0;
#pragma unroll
    for (int j = 0; j < 8; j++) {
      a0 += ds0[j * 32 + m];
      a1 += ds1[j * 32 + m];
      b0 += dq0[j * 32 + m];
      b1 += dq1[j * 32 + m];
    }
    atomicAdd(&st[2 * m], a0);
    atomicAdd(&st[2 * m + 1], a1);
    atomicAdd(&st[64 + 2 * m], b0);
    atomicAdd(&st[64 + 2 * m + 1], b1);
  }
}

// ================= cooperative mega kernel =================
__global__ __launch_bounds__(256, 4) void mega(Params P) {
  cg::grid_group grid = cg::this_grid();
  __shared__ __align__(16) int smem[9216];
  __shared__ float smu[64], sisd[64];
  int bid = blockIdx.x, t = threadIdx.x;
  int nblk = (int)gridDim.x;

  // phase 1: sort || gemm1 front
  if (bid < NW)
    sort_phase(bid, P.src, P.dst, P.barr, P.bofs, P.st, P.A, P.A2, P.e, P.nper, P.n, smem);
  else
    for (int tile = bid - NW; tile < P.split; tile += nblk - NW)
      gemm1_tile(tile, P.x, P.W1, P.A, P.n, smem);
  __threadfence();
  grid.sync();

  // phase 2: csrb || gemm1 tail
  if (bid < NB)
    csrb_phase(bid, P.barr, P.bofs, P.csr, P.seg2, P.dinv, P.n, P.nper, P.e, smem);
  else
    for (int tile = P.split + (bid - NW); tile < P.gG; tile += nblk - NW)
      gemm1_tile(tile, P.x, P.W1, P.A, P.n, smem);
  __threadfence();
  grid.sync();

  // phase 3: agg1 (weighted, A -> B fp16)
  {
    int lane = t & 63;
    int wid = bid * 4 + (t >> 6);
    for (int i = wid; i < P.n; i += nblk * 4)
      agg_node<true, true>(i, P.A, P.B, P.seg2, P.csr, P.dinv, P.b1, P.n, lane);
  }
  __threadfence();
  grid.sync();

  // phase 4: BN stats
  bnstats_phase(bid, nblk, P.B, P.st, P.n, smem);
  __threadfence();
  grid.sync();

  // phase 5: gemm2 (B -> A2)
  {
    if (t < 64) {
      double mu = P.st[t] / P.n;
      double var = P.st[64 + t] / P.n - mu * mu;
      smu[t] = (float)mu;
      sisd[t] = (float)(1.0 / sqrt(var + (double)BN_EPS));
    }
    __syncthreads();
    for (int tile = bid; tile < P.gG; tile += nblk)
      gemm2_tile(tile, P.B, P.W2, P.A2, P.n, P.dinv, P.gamma, P.beta, smu, sisd, smem);
  }
  __threadfence();
  grid.sync();

  // phase 6: agg2 (unweighted, A2 -> out fp32)
  {
    int lane = t & 63;
    int wid = bid * 4 + (t >> 6);
    for (int i = wid; i < P.n; i += nblk * 4)
      agg_node<false, false>(i, P.A2, P.out, P.seg2, P.csr, P.dinv, P.b2, P.n, lane);
  }
}

// ================= fallback kernels (same device code) =================
__global__ __launch_bounds__(256) void k_pg(Params P) {
  __shared__ __align__(16) int smem[9216];
  if (blockIdx.x < NW)
    sort_phase(blockIdx.x, P.src, P.dst, P.barr, P.bofs, P.st, P.A, P.A2, P.e,
               P.nper, P.n, smem);
  else
    for (int tile = blockIdx.x - NW; tile < P.gG; tile += (int)gridDim.x - NW)
      gemm1_tile(tile, P.x, P.W1, P.A, P.n, smem);
}

__global__ __launch_bounds__(256) void k_csrb(Params P) {
  __shared__ __align__(16) int smem[9216];
  csrb_phase(blockIdx.x, P.barr, P.bofs, P.csr, P.seg2, P.dinv, P.n, P.nper, P.e, smem);
}

template <bool WEIGHTED, bool FP16OUT>
__global__ __launch_bounds__(256) void k_aggk(Params P, const __half* H, void* O,
                                              const float* bias) {
  int wave = (blockIdx.x * 256 + threadIdx.x) >> 6;
  if (wave < P.n)
    agg_node<WEIGHTED, FP16OUT>(wave, H, O, P.seg2, P.csr, P.dinv, bias, P.n,
                                threadIdx.x & 63);
}

__global__ __launch_bounds__(256) void k_bnstats(Params P) {
  __shared__ __align__(16) int smem[2048];
  bnstats_phase(blockIdx.x, gridDim.x, P.B, P.st, P.n, smem);
}

__global__ __launch_bounds__(256) void k_gemm2(Params P) {
  __shared__ __align__(16) int smem[9216];
  __shared__ float smu[64], sisd[64];
  int t = threadIdx.x;
  if (t < 64) {
    double mu = P.st[t] / P.n;
    double var = P.st[64 + t] / P.n - mu * mu;
    smu[t] = (float)mu;
    sisd[t] = (float)(1.0 / sqrt(var + (double)BN_EPS));
  }
  gemm2_tile(blockIdx.x, P.B, P.W2, P.A2, P.n, P.dinv, P.gamma, P.beta, smu, sisd, smem);
}

extern "C" void kernel_launch(void* const* d_in, const int* in_sizes, int n_in,
                              void* d_out, int out_size, void* d_ws, size_t ws_size,
                              hipStream_t stream) {
  int n = in_sizes[0] / 64;
  int e = in_sizes[1] / 2;

  char* ws = (char*)d_ws;
  size_t p = 0;
  auto alloc = [&](size_t bytes) {
    void* r = ws + p;
    p += (bytes + 255) & ~(size_t)255;
    return r;
  };
  unsigned* barr = (unsigned*)alloc((size_t)(e + 256) * 4);
  int*      bofs = (int*)alloc((size_t)NW * (NB + 1) * 4);
  int*      csr  = (int*)alloc(((size_t)NB * BCAP + 256) * 4);
  int2*     seg2 = (int2*)alloc((size_t)n * 8);
  float*    dinv = (float*)alloc((size_t)(n + 1) * 4);
  double*   st   = (double*)alloc(128 * 8);
  __half*   A    = (__half*)alloc((size_t)(n + 1) * 64 * 2);
  __half*   B    = (__half*)alloc((size_t)n * 64 * 2);
  __half*   A2   = (__half*)alloc((size_t)(n + 1) * 64 * 2);

  Params P;
  P.src = (const int*)d_in[1];
  P.dst = (const int*)d_in[1] + e;
  P.barr = barr;
  P.bofs = bofs;
  P.csr = csr;
  P.seg2 = seg2;
  P.dinv = dinv;
  P.st = st;
  P.A = A;
  P.B = B;
  P.A2 = A2;
  P.out = (float*)d_out;
  P.x = (const float*)d_in[0];
  P.W1 = (const float*)d_in[2];
  P.b1 = (const float*)d_in[3];
  P.gamma = (const float*)d_in[4];
  P.beta = (const float*)d_in[5];
  P.W2 = (const float*)d_in[6];
  P.b2 = (const float*)d_in[7];
  P.n = n;
  P.e = e;
  P.nper = (n + NB - 1) / NB;
  P.gG = (n + 63) / 64;
  P.split = (P.gG * 2) / 3;

  void* args[] = {&P};
  hipError_t err =
      hipLaunchCooperativeKernel((const void*)mega, dim3(GRID), dim3(256), args, 0, stream);
  if (err != hipSuccess) {
    (void)hipGetLastError();  // clear sticky error; use proven multi-kernel path
    int gAgg = (n + 3) / 4;
    k_pg<<<NW + P.gG, 256, 0, stream>>>(P);
    k_csrb<<<NB, 256, 0, stream>>>(P);
    k_aggk<true, true><<<gAgg, 256, 0, stream>>>(P, P.A, P.B, P.b1);
    k_bnstats<<<256, 256, 0, stream>>>(P);
    k_gemm2<<<P.gG, 256, 0, stream>>>(P);
    k_aggk<false, false><<<gAgg, 256, 0, stream>>>(P, P.A2, P.out, P.b2);
  }
}

// Round 18
// 183.530 us; speedup vs baseline: 7.0367x; 7.0367x over previous
//
#include <hip/hip_runtime.h>
#include <hip/hip_fp16.h>

#define LEAKY 0.01f
#define BN_EPS 1e-5f
#define NB 512       // dst buckets
#define NW 512       // writer blocks
#define EMAX 4096    // max edges per bucket in LDS (mean 3125, +17 sigma)
#define BCAP 7168    // csr ints per bucket (x16-padded segments; max 4096+15*196=7036)

typedef int v4i __attribute__((ext_vector_type(4)));

// ---------------- merged: blocks [0,NW) bucket-sort edges; blocks [NW,..) do X@W1 ----
__global__ __launch_bounds__(256) void k_pg(const int* __restrict__ src,
                                            const int* __restrict__ dst,
                                            unsigned* __restrict__ barr,
                                            int* __restrict__ bofs,
                                            double* __restrict__ st,
                                            int e, int nper, int n,
                                            const float* __restrict__ X,
                                            const float* __restrict__ W,
                                            __half* __restrict__ Y) {
  __shared__ __align__(16) int smem_i[9216];  // 36 KB union
  int t = threadIdx.x;
  if (blockIdx.x < NW) {
    // ---- bucket-sort path ----
    int* lcnt = smem_i;          // [512]
    int* lofs = smem_i + 512;    // [512]
    int* lcur = smem_i + 1024;   // [512]
    int* sd   = smem_i + 1536;   // [256]
    int wb = blockIdx.x;
    if (wb == 0 && t < 128) st[t] = 0.0;  // folded memset
    int S = (e + NW - 1) / NW;
    int s0 = wb * S, s1 = min(e, s0 + S);
    lcnt[t] = 0;
    lcnt[t + 256] = 0;
    lcur[t] = 0;
    lcur[t + 256] = 0;
    __syncthreads();
    for (int i = s0 + t; i < s1; i += 256) atomicAdd(&lcnt[dst[i] / nper], 1);
    __syncthreads();
    int c0 = lcnt[2 * t], c1 = lcnt[2 * t + 1];
    int ts = c0 + c1;
    sd[t] = ts;
    __syncthreads();
    for (int off = 1; off < 256; off <<= 1) {
      int x = (t >= off) ? sd[t - off] : 0;
      __syncthreads();
      sd[t] += x;
      __syncthreads();
    }
    int run = sd[t] - ts;
    lofs[2 * t] = run;
    lofs[2 * t + 1] = run + c0;
    bofs[wb * (NB + 1) + 2 * t] = run;
    bofs[wb * (NB + 1) + 2 * t + 1] = run + c0;
    if (t == 255) bofs[wb * (NB + 1) + NB] = sd[255];
    __syncthreads();
    for (int i = s0 + t; i < s1; i += 256) {
      int d = dst[i];
      int b = d / nper;
      int r = atomicAdd(&lcur[b], 1);  // LDS cursor
      barr[s0 + lofs[b] + r] = ((unsigned)src[i] << 9) | (unsigned)(d - b * nper);
    }
  } else {
    // ---- GEMM path: Y[r](fp16) = X[r] @ W (raw; dinv scale applied later by csrb) ----
    float(*Ws)[68] = (float(*)[68])smem_i;
    float(*Xs)[68] = (float(*)[68])(smem_i + 4352);
    int rowbase = (blockIdx.x - NW) * 64;
#pragma unroll
    for (int p = 0; p < 4; p++) {
      int idx = (p * 256 + t) * 4;
      *(float4*)&Ws[idx >> 6][idx & 63] = *(const float4*)&W[idx];
      int r = idx >> 6, c = idx & 63;
      int gr = rowbase + r;
      float4 v = (gr < n) ? *(const float4*)&X[(size_t)gr * 64 + c]
                          : make_float4(0.f, 0.f, 0.f, 0.f);
      *(float4*)&Xs[r][c] = v;
    }
    __syncthreads();
    int r = t >> 2;
    int cq = t & 3;
    float acc[16];
#pragma unroll
    for (int j = 0; j < 16; j++) acc[j] = 0.f;
#pragma unroll 4
    for (int k = 0; k < 64; k++) {
      float xv = Xs[r][k];
#pragma unroll
      for (int j = 0; j < 16; j++) acc[j] += xv * Ws[k][cq * 16 + j];
    }
    int gr = rowbase + r;
    if (gr < n) {
      __half2 h2[8];
#pragma unroll
      for (int j = 0; j < 8; j++) h2[j] = __floats2half2_rn(acc[2 * j], acc[2 * j + 1]);
      __half* yp = &Y[(size_t)gr * 64 + cq * 16];
      *(int4*)yp = *(int4*)&h2[0];
      *(int4*)(yp + 8) = *(int4*)&h2[4];
    }
  }
}

// ---------------- per-bucket CSR build in LDS + in-place dinv pre-scale of A ----------------
__global__ __launch_bounds__(256) void k_csrb(const unsigned* __restrict__ barr,
                                              const int* __restrict__ bofs,
                                              int* __restrict__ csr,
                                              int2* __restrict__ seg2,
                                              float* __restrict__ dinv,
                                              __half* __restrict__ A,
                                              int n, int nper, int e) {
  __shared__ int eds[EMAX];
  __shared__ int cnt_[256], base_[256], sd[256];
  __shared__ int ssz[512], soff[512], sstart[512];
  int b = blockIdx.x, t = threadIdx.x;
  if (b == 0 && t < 32) ((unsigned*)(A + (size_t)n * 64))[t] = 0u;  // zero sentinel row n
  int S = (e + NW - 1) / NW;
  int lo = b * nper;
  int nn = min(nper, n - lo);
  if (nn < 0) nn = 0;
  // segment (start,size) for this bucket from each of 512 writers + scan (2/thread)
  int sa0 = bofs[(2 * t) * (NB + 1) + b];
  int se0 = bofs[(2 * t) * (NB + 1) + b + 1];
  int sa1 = bofs[(2 * t + 1) * (NB + 1) + b];
  int se1 = bofs[(2 * t + 1) * (NB + 1) + b + 1];
  int v0 = se0 - sa0, v1 = se1 - sa1;
  sstart[2 * t] = sa0;
  sstart[2 * t + 1] = sa1;
  ssz[2 * t] = v0;
  ssz[2 * t + 1] = v1;
  int ts = v0 + v1;
  sd[t] = ts;
  __syncthreads();
  for (int off = 1; off < 256; off <<= 1) {
    int x = (t >= off) ? sd[t - off] : 0;
    __syncthreads();
    sd[t] += x;
    __syncthreads();
  }
  int run = sd[t] - ts;
  soff[2 * t] = run;
  soff[2 * t + 1] = run + v0;
  __syncthreads();
  int total = min(sd[255], EMAX);
  // copy 512 writer segments (~6 edges each) into LDS: 8-lane groups
  int g8 = t >> 3, l8 = t & 7;
  for (int wb = g8; wb < NW; wb += 32) {
    int sz = ssz[wb], of = soff[wb];
    const unsigned* rp = barr + (size_t)wb * S + sstart[wb];
    for (int k = l8; k < sz && of + k < EMAX; k += 8) eds[of + k] = (int)rp[k];
  }
  cnt_[t] = 0;
  __syncthreads();
  for (int i = t; i < total; i += 256) atomicAdd(&cnt_[eds[i] & 511], 1);
  __syncthreads();
  int c = cnt_[t];
  int pc = (t < nn) ? ((c + 15) & ~15) : 0;
  sd[t] = pc;
  __syncthreads();
  for (int off = 1; off < 256; off <<= 1) {
    int x = (t >= off) ? sd[t - off] : 0;
    __syncthreads();
    sd[t] += x;
    __syncthreads();
  }
  base_[t] = sd[t] - pc;
  __syncthreads();
  float* fdv = (float*)sd;  // sd free after last scan
  int bb = b * BCAP;
  if (t < nn) {
    int ba = bb + base_[t];
    seg2[lo + t] = make_int2(ba, ba + pc);
    float dv = rsqrtf((float)(c + 1));  // +1 self-loop
    dinv[lo + t] = dv;
    fdv[t] = dv;
    for (int j = c; j < pc; j++) csr[ba + j] = n;  // sentinel -> zero row
  }
  __syncthreads();
  // in-place pre-scale of A rows [lo, lo+nn): A'[r] = A[r] * dinv[r]
  {
    int4* Ap = (int4*)(A + (size_t)lo * 64);
    for (int idx = t; idx < nn * 8; idx += 256) {
      float dv = fdv[idx >> 3];
      int4 v = Ap[idx];
      __half2* hp = (__half2*)&v;
#pragma unroll
      for (int q = 0; q < 4; q++) {
        float2 f = __half22float2(hp[q]);
        hp[q] = __floats2half2_rn(f.x * dv, f.y * dv);
      }
      Ap[idx] = v;
    }
  }
  __syncthreads();
  cnt_[t] = 0;
  __syncthreads();
  for (int i = t; i < total; i += 256) {
    int vv = eds[i];
    int lcl = vv & 511;
    int r = atomicAdd(&cnt_[lcl], 1);
    csr[bb + base_[lcl] + r] = vv >> 9;
  }
  if (b == 0 && t == 0) dinv[n] = 0.f;
}

// ---------------- gemm2: Y[r](fp16) = (BN_LeakyReLU(X[r]) @ W) * dinv[r] ----------------
__global__ __launch_bounds__(256) void k_gemm2(const __half* __restrict__ Xh,
                                               const float* __restrict__ W,
                                               __half* __restrict__ Y, int n,
                                               const float* __restrict__ dinv,
                                               const double* __restrict__ st,
                                               const float* __restrict__ gamma,
                                               const float* __restrict__ beta) {
  __shared__ float Ws[64][68];
  __shared__ float Xs[64][68];
  __shared__ float smu[64], sisd[64];
  int t = threadIdx.x;
  if (t < 64) {
    double mu = st[t] / n;
    double var = st[64 + t] / n - mu * mu;
    smu[t] = (float)mu;
    sisd[t] = (float)(1.0 / sqrt(var + (double)BN_EPS));
  }
  __syncthreads();
  int rowbase = blockIdx.x * 64;
#pragma unroll
  for (int p = 0; p < 4; p++) {
    int idx = (p * 256 + t) * 4;
    *(float4*)&Ws[idx >> 6][idx & 63] = *(const float4*)&W[idx];
  }
#pragma unroll
  for (int p = 0; p < 2; p++) {
    int idx = (p * 256 + t) * 8;
    int r = idx >> 6, c = idx & 63;
    int gr = rowbase + r;
    float vp[8];
    if (gr < n) {
      int4 hv = *(const int4*)&Xh[(size_t)gr * 64 + c];
      __half2* hp = (__half2*)&hv;
#pragma unroll
      for (int q = 0; q < 4; q++) {
        float2 f = __half22float2(hp[q]);
        vp[2 * q] = f.x;
        vp[2 * q + 1] = f.y;
      }
    } else {
#pragma unroll
      for (int q = 0; q < 8; q++) vp[q] = 0.f;
    }
#pragma unroll
    for (int q = 0; q < 8; q++) {
      float z = gamma[c + q] * (vp[q] - smu[c + q]) * sisd[c + q] + beta[c + q];
      Xs[r][c + q] = (z >= 0.f) ? z : LEAKY * z;
    }
  }
  __syncthreads();
  int r = t >> 2;
  int cq = t & 3;
  float acc[16];
#pragma unroll
  for (int j = 0; j < 16; j++) acc[j] = 0.f;
#pragma unroll 4
  for (int k = 0; k < 64; k++) {
    float xv = Xs[r][k];
#pragma unroll
    for (int j = 0; j < 16; j++) acc[j] += xv * Ws[k][cq * 16 + j];
  }
  int gr = rowbase + r;
  if (gr < n) {
    float dv = dinv[gr];  // pre-scale for layer-2 agg
    __half2 h2[8];
#pragma unroll
    for (int j = 0; j < 8; j++)
      h2[j] = __floats2half2_rn(acc[2 * j] * dv, acc[2 * j + 1] * dv);
    __half* yp = &Y[(size_t)gr * 64 + cq * 16];
    *(int4*)yp = *(int4*)&h2[0];
    *(int4*)(yp + 8) = *(int4*)&h2[4];
  }
}

// ---------------- gather aggregation (unweighted; H pre-scaled by dinv) ----------------
// O_i = dinv_i * (sum H[src] + H[i]) + b
template <bool FP16OUT>
__global__ __launch_bounds__(256) void k_agg(const __half* __restrict__ H,
                                             void* __restrict__ Optr,
                                             const int2* __restrict__ seg2,
                                             const int* __restrict__ csr,
                                             const float* __restrict__ dinv,
                                             const float* __restrict__ bias, int n) {
  int wave = (blockIdx.x * 256 + threadIdx.x) >> 6;
  int lane = threadIdx.x & 63;
  int i = wave;
  if (i >= n) return;
  float di = dinv[i];
  int2 sg = seg2[i];
  int s0 = sg.x, s1 = sg.y;
  int m = lane & 31;
  bool loA = lane < 32;
  float2 sf = __half22float2(*(const __half2*)&H[(size_t)i * 64 + 2 * m]);
  float a0 = loA ? sf.x : 0.f;
  float a1 = loA ? sf.y : 0.f;
  const v4i* cp = (const v4i*)csr;
  int j = s0 >> 2, jend = s1 >> 2;
  v4i q0 = cp[j];
  v4i q1 = cp[j + 1];
  v4i q2 = cp[j + 2];
  v4i q3 = cp[j + 3];
  for (; j < jend; j += 4) {
    v4i p0 = cp[j + 4];
    v4i p1 = cp[j + 5];
    v4i p2 = cp[j + 6];
    v4i p3 = cp[j + 7];
    int i0 = loA ? q0[0] : q0[1];
    int i1 = loA ? q0[2] : q0[3];
    int i2 = loA ? q1[0] : q1[1];
    int i3 = loA ? q1[2] : q1[3];
    int i4 = loA ? q2[0] : q2[1];
    int i5 = loA ? q2[2] : q2[3];
    int i6 = loA ? q3[0] : q3[1];
    int i7 = loA ? q3[2] : q3[3];
    float2 f0 = __half22float2(*(const __half2*)&H[(size_t)i0 * 64 + 2 * m]);
    float2 f1 = __half22float2(*(const __half2*)&H[(size_t)i1 * 64 + 2 * m]);
    float2 f2 = __half22float2(*(const __half2*)&H[(size_t)i2 * 64 + 2 * m]);
    float2 f3 = __half22float2(*(const __half2*)&H[(size_t)i3 * 64 + 2 * m]);
    float2 f4 = __half22float2(*(const __half2*)&H[(size_t)i4 * 64 + 2 * m]);
    float2 f5 = __half22float2(*(const __half2*)&H[(size_t)i5 * 64 + 2 * m]);
    float2 f6 = __half22float2(*(const __half2*)&H[(size_t)i6 * 64 + 2 * m]);
    float2 f7 = __half22float2(*(const __half2*)&H[(size_t)i7 * 64 + 2 * m]);
    a0 += f0.x + f1.x + f2.x + f3.x;
    a1 += f0.y + f1.y + f2.y + f3.y;
    a0 += f4.x + f5.x + f6.x + f7.x;
    a1 += f4.y + f5.y + f6.y + f7.y;
    q0 = p0;
    q1 = p1;
    q2 = p2;
    q3 = p3;
  }
  a0 += __shfl_xor(a0, 32, 64);
  a1 += __shfl_xor(a1, 32, 64);
  if (loA) {
    float2 bv = *(const float2*)&bias[2 * m];
    float o0 = di * a0 + bv.x;
    float o1 = di * a1 + bv.y;
    if constexpr (FP16OUT) {
      ((__half2*)Optr)[(size_t)i * 32 + m] = __floats2half2_rn(o0, o1);
    } else {
      float2 o;
      o.x = o0;
      o.y = o1;
      *(float2*)&((float*)Optr)[(size_t)i * 64 + 2 * m] = o;
    }
  }
}

// ---------------- BN batch stats over fp16 B ----------------
__global__ __launch_bounds__(256) void k_bnstats(const __half* __restrict__ H,
                                                 double* __restrict__ st, int n) {
  __shared__ double ds0[8][32], ds1[8][32], dq0[8][32], dq1[8][32];
  int t = threadIdx.x;
  int m = t & 31;
  int g = t >> 5;
  double s0 = 0.0, s1 = 0.0, q0 = 0.0, q1 = 0.0;
  const __half2* H2 = (const __half2*)H;
  for (int r = blockIdx.x * 8 + g; r < n; r += gridDim.x * 8) {
    float2 f = __half22float2(H2[(size_t)r * 32 + m]);
    s0 += f.x;
    s1 += f.y;
    q0 += (double)f.x * f.x;
    q1 += (double)f.y * f.y;
  }
  ds0[g][m] = s0;
  ds1[g][m] = s1;
  dq0[g][m] = q0;
  dq1[g][m] = q1;
  __syncthreads();
  if (g == 0) {
    double a0 = 0, a1 = 0, b0 = 0, b1 = 0;
#pragma unroll
    for (int j = 0; j < 8; j++) {
      a0 += ds0[j][m];
      a1 += ds1[j][m];
      b0 += dq0[j][m];
      b1 += dq1[j][m];
    }
    atomicAdd(&st[2 * m], a0);
    atomicAdd(&st[2 * m + 1], a1);
    atomicAdd(&st[64 + 2 * m], b0);
    atomicAdd(&st[64 + 2 * m + 1], b1);
  }
}

extern "C" void kernel_launch(void* const* d_in, const int* in_sizes, int n_in,
                              void* d_out, int out_size, void* d_ws, size_t ws_size,
                              hipStream_t stream) {
  const float* x     = (const float*)d_in[0];
  const int*   ei    = (const int*)d_in[1];
  const float* W1    = (const float*)d_in[2];
  const float* b1    = (const float*)d_in[3];
  const float* gamma = (const float*)d_in[4];
  const float* beta  = (const float*)d_in[5];
  const float* W2    = (const float*)d_in[6];
  const float* b2    = (const float*)d_in[7];
  float* out = (float*)d_out;

  int n = in_sizes[0] / 64;
  int e = in_sizes[1] / 2;
  const int* srcv = ei;
  const int* dstv = ei + e;
  int nper = (n + NB - 1) / NB;  // nodes per bucket (<=512 required by 9-bit packing)

  char* ws = (char*)d_ws;
  size_t p = 0;
  auto alloc = [&](size_t bytes) {
    void* r = ws + p;
    p += (bytes + 255) & ~(size_t)255;
    return r;
  };
  unsigned* barr = (unsigned*)alloc((size_t)(e + 256) * 4);
  int*      bofs = (int*)alloc((size_t)NW * (NB + 1) * 4);
  int*      csr  = (int*)alloc(((size_t)NB * BCAP + 256) * 4);
  int2*     seg2 = (int2*)alloc((size_t)n * 8);
  float*    dinv = (float*)alloc((size_t)(n + 1) * 4);
  double*   st   = (double*)alloc(128 * 8);
  __half*   A    = (__half*)alloc((size_t)(n + 1) * 64 * 2);  // activations (+ zero row n)
  __half*   B    = (__half*)alloc((size_t)n * 64 * 2);        // agg1 out, fp16

  int gG = (n + 63) / 64;
  int gAgg = (n + 3) / 4;

  k_pg<<<NW + gG, 256, 0, stream>>>(srcv, dstv, barr, bofs, st, e, nper, n, x, W1, A);
  k_csrb<<<NB, 256, 0, stream>>>(barr, bofs, csr, seg2, dinv, A, n, nper, e);
  k_agg<true><<<gAgg, 256, 0, stream>>>(A, B, seg2, csr, dinv, b1, n);
  k_bnstats<<<256, 256, 0, stream>>>(B, st, n);
  k_gemm2<<<gG, 256, 0, stream>>>(B, W2, A, n, dinv, st, gamma, beta);
  k_agg<false><<<gAgg, 256, 0, stream>>>(A, out, seg2, csr, dinv, b2, n);
}